// Round 1
// baseline (214.800 us; speedup 1.0000x reference)
//
#include <hip/hip_runtime.h>
#include <math.h>

#define HW 4096

// ---------------------------------------------------------------------------
// K1: 1x1 conv (QKV projection) + bias.
// x: [B][192][HW], W1: [576][192], b1: [576]
// out: [b][g][pix][d] with g = q3*6+head (18 groups), d in [0,32)  (d-contiguous)
// Block: 256 thr, computes 192 oc (one q3 slice) x 32 pixels.
// ---------------------------------------------------------------------------
__global__ __launch_bounds__(256) void k_qkv1(const float* __restrict__ x,
    const float* __restrict__ W1, const float* __restrict__ b1,
    float* __restrict__ out)
{
    __shared__ float smem[192 * 33];
    const int t = threadIdx.x;
    const int pix0 = blockIdx.x * 32;
    const int q3 = blockIdx.y;
    const int b = blockIdx.z;
    const float* xb = x + (size_t)b * 192 * HW;
    #pragma unroll
    for (int k = 0; k < 24; ++k) {
        int idx = t + k * 256;
        int c = idx >> 5, p = idx & 31;
        smem[c * 33 + p] = xb[(size_t)c * HW + pix0 + p];
    }
    __syncthreads();
    const int pixg = t & 7;          // 0..7 (4 pixels each)
    const int ocg = t >> 3;          // 0..31 (6 oc each)
    const int oc0 = ocg * 6;
    const float* Wr = W1 + (size_t)q3 * 192 * 192;
    float acc[6][4];
    #pragma unroll
    for (int j = 0; j < 6; ++j) {
        float bb = b1[q3 * 192 + oc0 + j];
        #pragma unroll
        for (int p = 0; p < 4; ++p) acc[j][p] = bb;
    }
    #pragma unroll 4
    for (int c = 0; c < 192; ++c) {
        float xv[4];
        #pragma unroll
        for (int p = 0; p < 4; ++p) xv[p] = smem[c * 33 + pixg * 4 + p];
        #pragma unroll
        for (int j = 0; j < 6; ++j) {
            float wv = Wr[(oc0 + j) * 192 + c];
            #pragma unroll
            for (int p = 0; p < 4; ++p) acc[j][p] = fmaf(wv, xv[p], acc[j][p]);
        }
    }
    __syncthreads();
    // stage results for coalesced writes: ys[oc][pix], stride 33
    #pragma unroll
    for (int j = 0; j < 6; ++j) {
        #pragma unroll
        for (int p = 0; p < 4; ++p)
            smem[(oc0 + j) * 33 + pixg * 4 + p] = acc[j][p];
    }
    __syncthreads();
    float* ob = out + ((size_t)b * 18 + q3 * 6) * HW * 32;
    #pragma unroll
    for (int k = 0; k < 24; ++k) {
        int idx = t + k * 256;
        int d = idx & 31;
        int pix = (idx >> 5) & 31;
        int head = idx >> 10;
        ob[((size_t)head * HW + pix0 + pix) * 32 + d] = smem[(head * 32 + d) * 33 + pix];
    }
}

// ---------------------------------------------------------------------------
// K2: depthwise 3x3 conv, SAME zero-pad, + bias.
// layout in/out: [b][g][pix][d], weight channel c = g*32 + d.
// ---------------------------------------------------------------------------
__global__ __launch_bounds__(256) void k_dw(const float* __restrict__ in,
    const float* __restrict__ W2, const float* __restrict__ b2,
    float* __restrict__ out)
{
    const int idx = blockIdx.x * 256 + threadIdx.x;   // < 2*18*4096*32
    const int d = idx & 31;
    const int pix = (idx >> 5) & (HW - 1);
    const int bg = idx >> 17;                          // b*18+g, 0..35
    const int g = (bg >= 18) ? (bg - 18) : bg;
    const int c = g * 32 + d;
    const int i = pix >> 6, j = pix & 63;
    const float* base = in + ((size_t)bg << 17);
    const float* wc = W2 + c * 9;
    float s = b2[c];
    #pragma unroll
    for (int di = -1; di <= 1; ++di) {
        int ii = i + di;
        if (ii < 0 || ii > 63) continue;
        #pragma unroll
        for (int dj = -1; dj <= 1; ++dj) {
            int jj = j + dj;
            if (jj < 0 || jj > 63) continue;
            s = fmaf(base[(size_t)(((ii << 6) + jj) << 5) + d], wc[(di + 1) * 3 + (dj + 1)], s);
        }
    }
    out[idx] = s;
}

// ---------------------------------------------------------------------------
// K3: fused neighborhood attention (l2norm q/k, QK^T + rpb, softmax, PV).
// qkv layout: [b][q3*6+head][pix][32].  out: [b][pix][head*32+d] (c-contiguous).
// One block = (b, head, 8x8 pixel tile), 64 threads, 1 thread per pixel.
// k/v halo (14x14x32) staged in LDS, stride 36 floats -> all ds_read_b128,
// balanced bank-quad pattern.
// ---------------------------------------------------------------------------
__global__ __launch_bounds__(64) void k_attn(const float* __restrict__ qkv,
    const float* __restrict__ temp, const float* __restrict__ rpb,
    float* __restrict__ out)
{
    __shared__ __align__(16) float ks[196 * 36];
    __shared__ __align__(16) float vs[196 * 36];
    __shared__ float rpbs[169];
    const int t = threadIdx.x;
    const int ti = blockIdx.x >> 3, tj = blockIdx.x & 7;
    const int head = blockIdx.y;
    const int b = blockIdx.z;
    const int i0 = ti * 8, j0 = tj * 8;
    const int r0 = min(max(i0 - 3, 0), 50);   // 14-row window covers all nbrs of the tile
    const int c0 = min(max(j0 - 3, 0), 50);
    const float* kbase = qkv + (((size_t)b * 18 + 6 + head) << 17);
    const float* vbase = qkv + (((size_t)b * 18 + 12 + head) << 17);

    for (int p = t; p < 196; p += 64) {
        int r = p / 14, cc = p - r * 14;
        size_t goff = (size_t)((((r0 + r) << 6) + (c0 + cc)) << 5);
        float kv[32];
        #pragma unroll
        for (int d4 = 0; d4 < 8; ++d4) {
            float4 k4 = *(const float4*)(kbase + goff + d4 * 4);
            kv[d4 * 4 + 0] = k4.x; kv[d4 * 4 + 1] = k4.y;
            kv[d4 * 4 + 2] = k4.z; kv[d4 * 4 + 3] = k4.w;
            float4 v4 = *(const float4*)(vbase + goff + d4 * 4);
            *(float4*)&vs[p * 36 + d4 * 4] = v4;
        }
        float s = 0.f;
        #pragma unroll
        for (int d = 0; d < 32; ++d) s = fmaf(kv[d], kv[d], s);
        float rinv = 1.0f / fmaxf(sqrtf(s), 1e-12f);
        #pragma unroll
        for (int d4 = 0; d4 < 8; ++d4) {
            *(float4*)&ks[p * 36 + d4 * 4] = make_float4(
                kv[d4 * 4 + 0] * rinv, kv[d4 * 4 + 1] * rinv,
                kv[d4 * 4 + 2] * rinv, kv[d4 * 4 + 3] * rinv);
        }
    }
    for (int idx = t; idx < 169; idx += 64) rpbs[idx] = rpb[head * 169 + idx];

    // own q (registers only), l2-normalized
    const int li = t >> 3, lj = t & 7;
    const int i = i0 + li, j = j0 + lj;
    const float* qbase = qkv + (((size_t)b * 18 + head) << 17) + ((size_t)((i << 6) + j) << 5);
    float q[32];
    #pragma unroll
    for (int d4 = 0; d4 < 8; ++d4) {
        float4 q4 = *(const float4*)(qbase + d4 * 4);
        q[d4 * 4 + 0] = q4.x; q[d4 * 4 + 1] = q4.y;
        q[d4 * 4 + 2] = q4.z; q[d4 * 4 + 3] = q4.w;
    }
    float qs = 0.f;
    #pragma unroll
    for (int d = 0; d < 32; ++d) qs = fmaf(q[d], q[d], qs);
    float qinv = 1.0f / fmaxf(sqrtf(qs), 1e-12f);
    #pragma unroll
    for (int d = 0; d < 32; ++d) q[d] *= qinv;
    __syncthreads();

    const int si = min(max(i - 3, 0), 57), sj = min(max(j - 3, 0), 57);
    const int pr0 = si - r0, pc0 = sj - c0;           // both in [0,7]
    const float th = temp[head];
    const int bi0 = (si - i + 6) * 13 + (sj - j + 6); // rel-bias base index
    float a[49];
    #pragma unroll
    for (int ki = 0; ki < 7; ++ki) {
        #pragma unroll
        for (int kj = 0; kj < 7; ++kj) {
            const float* kp = &ks[((pr0 + ki) * 14 + pc0 + kj) * 36];
            float dot = 0.f;
            #pragma unroll
            for (int d4 = 0; d4 < 8; ++d4) {
                float4 k4 = *(const float4*)(kp + d4 * 4);
                dot = fmaf(q[d4 * 4 + 0], k4.x, dot);
                dot = fmaf(q[d4 * 4 + 1], k4.y, dot);
                dot = fmaf(q[d4 * 4 + 2], k4.z, dot);
                dot = fmaf(q[d4 * 4 + 3], k4.w, dot);
            }
            a[ki * 7 + kj] = (dot + rpbs[bi0 + ki * 13 + kj]) * th;
        }
    }
    float m = a[0];
    #pragma unroll
    for (int kk = 1; kk < 49; ++kk) m = fmaxf(m, a[kk]);
    float ssum = 0.f;
    #pragma unroll
    for (int kk = 0; kk < 49; ++kk) { a[kk] = expf(a[kk] - m); ssum += a[kk]; }
    const float rs = 1.0f / ssum;

    float o[32];
    #pragma unroll
    for (int d = 0; d < 32; ++d) o[d] = 0.f;
    #pragma unroll
    for (int ki = 0; ki < 7; ++ki) {
        #pragma unroll
        for (int kj = 0; kj < 7; ++kj) {
            const float* vp = &vs[((pr0 + ki) * 14 + pc0 + kj) * 36];
            const float w = a[ki * 7 + kj];
            #pragma unroll
            for (int d4 = 0; d4 < 8; ++d4) {
                float4 v4 = *(const float4*)(vp + d4 * 4);
                o[d4 * 4 + 0] = fmaf(w, v4.x, o[d4 * 4 + 0]);
                o[d4 * 4 + 1] = fmaf(w, v4.y, o[d4 * 4 + 1]);
                o[d4 * 4 + 2] = fmaf(w, v4.z, o[d4 * 4 + 2]);
                o[d4 * 4 + 3] = fmaf(w, v4.w, o[d4 * 4 + 3]);
            }
        }
    }
    float* ob = out + ((size_t)b * HW + (i << 6) + j) * 192 + head * 32;
    #pragma unroll
    for (int d4 = 0; d4 < 8; ++d4) {
        *(float4*)(ob + d4 * 4) = make_float4(
            o[d4 * 4 + 0] * rs, o[d4 * 4 + 1] * rs,
            o[d4 * 4 + 2] * rs, o[d4 * 4 + 3] * rs);
    }
}

// ---------------------------------------------------------------------------
// K4: 1x1 output projection + bias.
// in: [b][pix][192] (c-contiguous), Wp: [192][192], out: [B][192][HW] (NCHW)
// ---------------------------------------------------------------------------
__global__ __launch_bounds__(256) void k_proj(const float* __restrict__ in,
    const float* __restrict__ Wp, const float* __restrict__ bp,
    float* __restrict__ out)
{
    __shared__ float smem[192 * 33];
    const int t = threadIdx.x;
    const int pix0 = blockIdx.x * 32;
    const int b = blockIdx.y;
    const float* ib = in + ((size_t)b * HW + pix0) * 192;
    #pragma unroll
    for (int k = 0; k < 24; ++k) {
        int idx = t + k * 256;
        int p = idx / 192, c = idx - p * 192;
        smem[c * 33 + p] = ib[idx];
    }
    __syncthreads();
    const int pixg = t & 7, ocg = t >> 3, oc0 = ocg * 6;
    float acc[6][4];
    #pragma unroll
    for (int j = 0; j < 6; ++j) {
        float bb = bp[oc0 + j];
        #pragma unroll
        for (int p = 0; p < 4; ++p) acc[j][p] = bb;
    }
    #pragma unroll 4
    for (int c = 0; c < 192; ++c) {
        float xv[4];
        #pragma unroll
        for (int p = 0; p < 4; ++p) xv[p] = smem[c * 33 + pixg * 4 + p];
        #pragma unroll
        for (int j = 0; j < 6; ++j) {
            float wv = Wp[(oc0 + j) * 192 + c];
            #pragma unroll
            for (int p = 0; p < 4; ++p) acc[j][p] = fmaf(wv, xv[p], acc[j][p]);
        }
    }
    __syncthreads();
    #pragma unroll
    for (int j = 0; j < 6; ++j) {
        #pragma unroll
        for (int p = 0; p < 4; ++p)
            smem[(oc0 + j) * 33 + pixg * 4 + p] = acc[j][p];
    }
    __syncthreads();
    float* ob = out + (size_t)b * 192 * HW;
    #pragma unroll
    for (int k = 0; k < 24; ++k) {
        int idx = t + k * 256;
        int pix = idx & 31, oc = idx >> 5;
        ob[(size_t)oc * HW + pix0 + pix] = smem[oc * 33 + pix];
    }
}

extern "C" void kernel_launch(void* const* d_in, const int* in_sizes, int n_in,
                              void* d_out, int out_size, void* d_ws, size_t ws_size,
                              hipStream_t stream) {
    const float* x    = (const float*)d_in[0];
    const float* W1   = (const float*)d_in[1];
    const float* b1   = (const float*)d_in[2];
    const float* W2   = (const float*)d_in[3];
    const float* b2   = (const float*)d_in[4];
    const float* temp = (const float*)d_in[5];
    const float* rpb  = (const float*)d_in[6];
    const float* Wp   = (const float*)d_in[7];
    const float* bp   = (const float*)d_in[8];
    float* out = (float*)d_out;

    const size_t qkv_elems = (size_t)2 * 18 * HW * 32;   // 4,718,592 floats
    float* qkv1 = (float*)d_ws;               // [b][g][pix][d]
    float* qkv2 = qkv1 + qkv_elems;           // after depthwise conv
    float* attn_out = qkv1;                   // reuse: qkv1 dead after k_dw

    k_qkv1<<<dim3(128, 3, 2), 256, 0, stream>>>(x, W1, b1, qkv1);
    k_dw<<<dim3((unsigned)(qkv_elems / 256)), 256, 0, stream>>>(qkv1, W2, b2, qkv2);
    k_attn<<<dim3(64, 6, 2), 64, 0, stream>>>(qkv2, temp, rpb, attn_out);
    k_proj<<<dim3(128, 2), 256, 0, stream>>>(attn_out, Wp, bp, out);
}

// Round 2
// 177.968 us; speedup vs baseline: 1.2070x; 1.2070x over previous
//
#include <hip/hip_runtime.h>
#include <math.h>

#define HW 4096

// ws layout (floats):
//   Wt1   @ 0        : 192*576  = 110592   (Wt1[c*576+oc] = W1[oc*192+c])
//   Wtp   @ 110592   : 192*192  = 36864    (Wtp[c*192+oc] = Wp[oc*192+c])
//   W2t   @ 147456   : 9*576    = 5184     (W2t[tap*576+c] = W2[c*9+tap])
//   qkv1  @ 152640   : 2*18*4096*32 = 4718592   [b][g][pix][d], g=q3*6+head
//   attnO @ 4871232  : 2*192*4096   = 1572864   [b][c][pix] (d-major)

// ---------------------------------------------------------------------------
// K0: weight transposes so GEMM weight reads are wave-uniform (s_load) and
// depthwise weights are tap-major for LDS staging.
// ---------------------------------------------------------------------------
__global__ __launch_bounds__(256) void k_wt(const float* __restrict__ W1,
    const float* __restrict__ Wp, const float* __restrict__ W2,
    float* __restrict__ Wt1, float* __restrict__ Wtp, float* __restrict__ W2t)
{
    int idx = blockIdx.x * 256 + threadIdx.x;
    if (idx < 110592) {                     // Wt1
        int c = idx / 576, oc = idx - c * 576;
        Wt1[idx] = W1[oc * 192 + c];
    } else if (idx < 110592 + 36864) {      // Wtp
        int r = idx - 110592;
        int c = r / 192, oc = r - c * 192;
        Wtp[r] = Wp[oc * 192 + c];
    } else if (idx < 110592 + 36864 + 5184) { // W2t
        int r = idx - 147456;
        int tap = r / 576, c = r - tap * 576;
        W2t[r] = W2[c * 9 + tap];
    }
}

// ---------------------------------------------------------------------------
// K1: 1x1 QKV conv as scalar-broadcast GEMM.
// Block: 256 px (one per thread) x 32 oc (register tile), K=192.
// Weights via wave-uniform s_load_dwordx16; x via coalesced b32 loads.
// out: [b][g][pix][32] d-contiguous, g = blockIdx.y = q3*6+head.
// ---------------------------------------------------------------------------
__global__ __launch_bounds__(256) void k_qkv1(const float* __restrict__ x,
    const float* __restrict__ Wt1, const float* __restrict__ b1,
    float* __restrict__ out)
{
    const int t = threadIdx.x;
    const int px = blockIdx.x * 256 + t;
    const int g = blockIdx.y;            // 0..17
    const int b = blockIdx.z;
    const int oc0 = g * 32;
    const float* xb = x + (size_t)b * 192 * HW + px;
    float acc[32];
    #pragma unroll
    for (int k = 0; k < 32; ++k) acc[k] = b1[oc0 + k];
    #pragma unroll 4
    for (int c = 0; c < 192; ++c) {
        float xv = xb[(size_t)c * HW];
        const float* wr = Wt1 + c * 576 + oc0;   // wave-uniform
        #pragma unroll
        for (int k = 0; k < 32; ++k) acc[k] = fmaf(wr[k], xv, acc[k]);
    }
    float* ob = out + (((size_t)(b * 18 + g) << 12) + px) * 32;
    #pragma unroll
    for (int k4 = 0; k4 < 8; ++k4)
        *(float4*)(ob + k4 * 4) = make_float4(acc[k4*4], acc[k4*4+1], acc[k4*4+2], acc[k4*4+3]);
}

// ---------------------------------------------------------------------------
// K2: fused depthwise-3x3 + neighborhood attention.
// Block: 256 thr = (b, head, 8x8 px tile); 4 lanes per pixel (d-split).
// Staging computes dw-conv(+bias) of k/v for the 14x14 halo into LDS
// (k fp32 stride 36, v bf16 stride 40-shorts), and of q into registers.
// QK^T uses rinv-deferred l2norm of k; softmax per lane; PV from bf16 LDS.
// Output d-major: [b][c][pix].
// ---------------------------------------------------------------------------
__device__ inline unsigned bfpack2(float x, float y) {
    unsigned ux = __float_as_uint(x), uy = __float_as_uint(y);
    ux = (ux + 0x7fffu + ((ux >> 16) & 1u)) >> 16;
    uy = (uy + 0x7fffu + ((uy >> 16) & 1u)) & 0xffff0000u;
    return ux | uy;
}

__global__ __launch_bounds__(256) void k_attn(const float* __restrict__ qkv1,
    const float* __restrict__ W2t, const float* __restrict__ b2,
    const float* __restrict__ temp, const float* __restrict__ rpb,
    float* __restrict__ out)
{
    __shared__ __align__(16) float    ks[196 * 36];     // fp32 k halo
    __shared__ __align__(16) unsigned vs[196 * 20];     // bf16 v halo (packed)
    __shared__ float rinvs[196];
    __shared__ float rpbs[169];
    __shared__ __align__(16) float wsm[3 * 288];        // [plane][tap][32ch]
    __shared__ __align__(16) float bsm[96];             // [plane][32ch]

    const int t = threadIdx.x;
    const int ti = blockIdx.x >> 3, tj = blockIdx.x & 7;
    const int head = blockIdx.y;
    const int b = blockIdx.z;
    const int i0 = ti * 8, j0 = tj * 8;
    const int r0 = min(max(i0 - 3, 0), 50);
    const int c0 = min(max(j0 - 3, 0), 50);

    // ---- cooperative stage of dw weights / bias / rpb ----
    for (int idx = t; idx < 864; idx += 256) {
        int pl = idx / 288, rem = idx - pl * 288;
        int tap = rem >> 5, ch = rem & 31;
        wsm[idx] = W2t[tap * 576 + pl * 192 + head * 32 + ch];
    }
    for (int idx = t; idx < 96; idx += 256) {
        int pl = idx >> 5, ch = idx & 31;
        bsm[idx] = b2[pl * 192 + head * 32 + ch];
    }
    for (int idx = t; idx < 169; idx += 256) rpbs[idx] = rpb[head * 169 + idx];
    __syncthreads();

    // ---- per-lane dw weights into registers (chunk d4 = t&7, 4 ch each) ----
    const int d4 = t & 7;
    const int prow = t >> 3;
    float4 wk4[9], wv4[9];
    #pragma unroll
    for (int tap = 0; tap < 9; ++tap) {
        wk4[tap] = *(const float4*)&wsm[288 + tap * 32 + d4 * 4];
        wv4[tap] = *(const float4*)&wsm[576 + tap * 32 + d4 * 4];
    }
    const float4 bk4 = *(const float4*)&bsm[32 + d4 * 4];
    const float4 bv4 = *(const float4*)&bsm[64 + d4 * 4];
    const float* kplane = qkv1 + ((size_t)(b * 18 + 6 + head) << 17);
    const float* vplane = qkv1 + ((size_t)(b * 18 + 12 + head) << 17);

    // ---- halo staging: dw-conv of k and v, 196 positions x 8 chunks ----
    #pragma unroll
    for (int ph = 0; ph < 7; ++ph) {
        int p = prow + ph * 32;
        bool act = p < 196;
        float4 sk = bk4, sv = bv4;
        if (act) {
            int r = (p * 2341) >> 15;      // p/14
            int cc = p - r * 14;
            int gi = r0 + r, gj = c0 + cc;
            #pragma unroll
            for (int di = -1; di <= 1; ++di) {
                int ii = gi + di;
                if (ii < 0 || ii > 63) continue;
                #pragma unroll
                for (int dj = -1; dj <= 1; ++dj) {
                    int jj = gj + dj;
                    if (jj < 0 || jj > 63) continue;
                    int tap = (di + 1) * 3 + dj + 1;
                    size_t off = ((size_t)((ii << 6) + jj) << 5) + d4 * 4;
                    float4 kx = *(const float4*)(kplane + off);
                    float4 vx = *(const float4*)(vplane + off);
                    sk.x = fmaf(kx.x, wk4[tap].x, sk.x);
                    sk.y = fmaf(kx.y, wk4[tap].y, sk.y);
                    sk.z = fmaf(kx.z, wk4[tap].z, sk.z);
                    sk.w = fmaf(kx.w, wk4[tap].w, sk.w);
                    sv.x = fmaf(vx.x, wv4[tap].x, sv.x);
                    sv.y = fmaf(vx.y, wv4[tap].y, sv.y);
                    sv.z = fmaf(vx.z, wv4[tap].z, sv.z);
                    sv.w = fmaf(vx.w, wv4[tap].w, sv.w);
                }
            }
            *(float4*)&ks[p * 36 + d4 * 4] = sk;
            uint2 pv;
            pv.x = bfpack2(sv.x, sv.y);
            pv.y = bfpack2(sv.z, sv.w);
            *(uint2*)&vs[p * 20 + d4 * 2] = pv;
        }
        float ss = act ? (sk.x*sk.x + sk.y*sk.y + sk.z*sk.z + sk.w*sk.w) : 0.f;
        ss += __shfl_xor(ss, 1);
        ss += __shfl_xor(ss, 2);
        ss += __shfl_xor(ss, 4);
        if (act && d4 == 0) rinvs[p] = 1.0f / fmaxf(sqrtf(ss), 1e-12f);
    }

    // ---- own q: dw-conv into registers (lane owns 8 ch: dsub*8..) ----
    const int pixel = t >> 2, dsub = t & 3;
    const int li = pixel >> 3, lj = pixel & 7;
    const int i = i0 + li, j = j0 + lj;
    const float* qplane = qkv1 + ((size_t)(b * 18 + head) << 17);
    float4 qa = *(const float4*)&bsm[dsub * 8];
    float4 qb = *(const float4*)&bsm[dsub * 8 + 4];
    #pragma unroll
    for (int di = -1; di <= 1; ++di) {
        int ii = i + di;
        if (ii < 0 || ii > 63) continue;
        #pragma unroll
        for (int dj = -1; dj <= 1; ++dj) {
            int jj = j + dj;
            if (jj < 0 || jj > 63) continue;
            int tap = (di + 1) * 3 + dj + 1;
            size_t off = ((size_t)((ii << 6) + jj) << 5) + dsub * 8;
            float4 xa = *(const float4*)(qplane + off);
            float4 xb = *(const float4*)(qplane + off + 4);
            float4 wa = *(const float4*)&wsm[tap * 32 + dsub * 8];
            float4 wb = *(const float4*)&wsm[tap * 32 + dsub * 8 + 4];
            qa.x = fmaf(xa.x, wa.x, qa.x); qa.y = fmaf(xa.y, wa.y, qa.y);
            qa.z = fmaf(xa.z, wa.z, qa.z); qa.w = fmaf(xa.w, wa.w, qa.w);
            qb.x = fmaf(xb.x, wb.x, qb.x); qb.y = fmaf(xb.y, wb.y, qb.y);
            qb.z = fmaf(xb.z, wb.z, qb.z); qb.w = fmaf(xb.w, wb.w, qb.w);
        }
    }
    float qs = qa.x*qa.x + qa.y*qa.y + qa.z*qa.z + qa.w*qa.w
             + qb.x*qb.x + qb.y*qb.y + qb.z*qb.z + qb.w*qb.w;
    qs += __shfl_xor(qs, 1);
    qs += __shfl_xor(qs, 2);
    float qinv = 1.0f / fmaxf(sqrtf(qs), 1e-12f);
    qa.x *= qinv; qa.y *= qinv; qa.z *= qinv; qa.w *= qinv;
    qb.x *= qinv; qb.y *= qinv; qb.z *= qinv; qb.w *= qinv;
    __syncthreads();

    // ---- QK^T + bias + temperature ----
    const int si = min(max(i - 3, 0), 57), sj = min(max(j - 3, 0), 57);
    const int pr0 = si - r0, pc0 = sj - c0;
    const float th = temp[head];
    const int bi0 = (si - i + 6) * 13 + (sj - j + 6);
    const int nbase = pr0 * 14 + pc0;
    float a[49];
    #pragma unroll
    for (int ki = 0; ki < 7; ++ki) {
        #pragma unroll
        for (int kj = 0; kj < 7; ++kj) {
            int nb = nbase + ki * 14 + kj;
            const float* kp = &ks[nb * 36 + dsub * 8];
            float4 ka = *(const float4*)kp;
            float4 kb = *(const float4*)(kp + 4);
            float dot = qa.x * ka.x;
            dot = fmaf(qa.y, ka.y, dot); dot = fmaf(qa.z, ka.z, dot);
            dot = fmaf(qa.w, ka.w, dot); dot = fmaf(qb.x, kb.x, dot);
            dot = fmaf(qb.y, kb.y, dot); dot = fmaf(qb.z, kb.z, dot);
            dot = fmaf(qb.w, kb.w, dot);
            dot += __shfl_xor(dot, 1);
            dot += __shfl_xor(dot, 2);
            a[ki * 7 + kj] = fmaf(dot, rinvs[nb], rpbs[bi0 + ki * 13 + kj]) * th;
        }
    }

    // ---- softmax (redundant x4 lanes) ----
    float m = a[0];
    #pragma unroll
    for (int kk = 1; kk < 49; ++kk) m = fmaxf(m, a[kk]);
    float ssum = 0.f;
    #pragma unroll
    for (int kk = 0; kk < 49; ++kk) { a[kk] = __expf(a[kk] - m); ssum += a[kk]; }
    const float rs = 1.0f / ssum;

    // ---- PV from bf16 LDS ----
    float o[8];
    #pragma unroll
    for (int d = 0; d < 8; ++d) o[d] = 0.f;
    #pragma unroll
    for (int ki = 0; ki < 7; ++ki) {
        #pragma unroll
        for (int kj = 0; kj < 7; ++kj) {
            int nb = nbase + ki * 14 + kj;
            uint4 uv = *(const uint4*)&vs[nb * 20 + dsub * 4];
            float w = a[ki * 7 + kj];
            o[0] = fmaf(w, __uint_as_float(uv.x << 16),        o[0]);
            o[1] = fmaf(w, __uint_as_float(uv.x & 0xffff0000u), o[1]);
            o[2] = fmaf(w, __uint_as_float(uv.y << 16),        o[2]);
            o[3] = fmaf(w, __uint_as_float(uv.y & 0xffff0000u), o[3]);
            o[4] = fmaf(w, __uint_as_float(uv.z << 16),        o[4]);
            o[5] = fmaf(w, __uint_as_float(uv.z & 0xffff0000u), o[5]);
            o[6] = fmaf(w, __uint_as_float(uv.w << 16),        o[6]);
            o[7] = fmaf(w, __uint_as_float(uv.w & 0xffff0000u), o[7]);
        }
    }
    float* ob = out + ((size_t)(b * 192 + head * 32 + dsub * 8) << 12) + (i << 6) + j;
    #pragma unroll
    for (int dd = 0; dd < 8; ++dd) ob[(size_t)dd << 12] = o[dd] * rs;
}

// ---------------------------------------------------------------------------
// K3: 1x1 output projection, scalar-broadcast GEMM.
// Block: 256 px x 8 oc, K=192. in: [b][c][pix]; out NCHW [b][oc][pix].
// ---------------------------------------------------------------------------
__global__ __launch_bounds__(256) void k_proj(const float* __restrict__ in,
    const float* __restrict__ Wtp, const float* __restrict__ bp,
    float* __restrict__ out)
{
    const int t = threadIdx.x;
    const int px = blockIdx.x * 256 + t;
    const int g = blockIdx.y;        // 0..23
    const int b = blockIdx.z;
    const int oc0 = g * 8;
    const float* ib = in + (size_t)b * 192 * HW + px;
    float acc[8];
    #pragma unroll
    for (int k = 0; k < 8; ++k) acc[k] = bp[oc0 + k];
    #pragma unroll 4
    for (int c = 0; c < 192; ++c) {
        float xv = ib[(size_t)c * HW];
        const float* wr = Wtp + c * 192 + oc0;   // wave-uniform
        #pragma unroll
        for (int k = 0; k < 8; ++k) acc[k] = fmaf(wr[k], xv, acc[k]);
    }
    float* ob = out + ((size_t)(b * 192 + oc0)) * HW + px;
    #pragma unroll
    for (int k = 0; k < 8; ++k) ob[(size_t)k * HW] = acc[k];
}

extern "C" void kernel_launch(void* const* d_in, const int* in_sizes, int n_in,
                              void* d_out, int out_size, void* d_ws, size_t ws_size,
                              hipStream_t stream) {
    const float* x    = (const float*)d_in[0];
    const float* W1   = (const float*)d_in[1];
    const float* b1   = (const float*)d_in[2];
    const float* W2   = (const float*)d_in[3];
    const float* b2   = (const float*)d_in[4];
    const float* temp = (const float*)d_in[5];
    const float* rpb  = (const float*)d_in[6];
    const float* Wp   = (const float*)d_in[7];
    const float* bp   = (const float*)d_in[8];
    float* out = (float*)d_out;

    float* ws    = (float*)d_ws;
    float* Wt1   = ws;
    float* Wtp   = ws + 110592;
    float* W2t   = ws + 147456;
    float* qkv1  = ws + 152640;
    float* attnO = ws + 4871232;

    k_wt  <<<dim3(597), 256, 0, stream>>>(W1, Wp, W2, Wt1, Wtp, W2t);
    k_qkv1<<<dim3(16, 18, 2), 256, 0, stream>>>(x, Wt1, b1, qkv1);
    k_attn<<<dim3(64, 6, 2), 256, 0, stream>>>(qkv1, W2t, b2, temp, rpb, attnO);
    k_proj<<<dim3(16, 24, 2), 256, 0, stream>>>(attnO, Wtp, bp, out);
}